// Round 5
// baseline (292.327 us; speedup 1.0000x reference)
//
#include <hip/hip_runtime.h>
#include <hip/hip_bf16.h>

// C[M,N] = A[M,K] @ B[N,K]^T, fp32 in/out, bf16 MFMA.
// R5: cvt-A pass ELIMINATED. A is consumed fp32 directly by the GEMM via
//   reg-staging (8 float4 loads/tile/thread, issued 1 tile ahead) ->
//   vmcnt(2) after the MFMA cluster -> 16 packed cvt -> 4 ds_write_b128
//   into the SAME swizzled LDS layout (chunk tid&7 -> slot ^(row&7)).
//   Saves 201 MB of cvt-A traffic, adds 67 MB GEMM A-read (fp32 vs bf16):
//   net -134 MB HBM. B keeps gload_lds + a tiny B-only cvt (25 MB, ~4us).
// GEMM: 256x128/BK=64, 512 thr = 8 waves, grid 256 = 1 block/CU,
//   2 waves/SIMD (R3: 1 wave/SIMD is fatal). K-SPLIT WAVE PAIRS: 4 spatial
//   128x64 tiles x 2 K-halves; 12 ds_read_b128 per 32 MFMA (0.375 ratio);
//   cross-wave add once at end. 3-buffer LDS ring (144 KiB), ONE barrier
//   per K-tile (ring slack bounds drift; staged buffer was last read at
//   t-1). Counted vmcnt only; lgkmcnt(0) before each barrier publishes
//   ds_writes. XOR bank-swizzle (measured 0 conflicts). XCD-bijective
//   block swizzle (A+B fetch = compulsory).

typedef __bf16 bf16x8 __attribute__((ext_vector_type(8)));
typedef float f32x4 __attribute__((ext_vector_type(4)));

#define BM 256
#define BN 128
#define BK 64
#define NBUF 3
// fallback tile
#define TM 128
#define TN 128

#define MFMA16(a_, b_, c_) \
    __builtin_amdgcn_mfma_f32_16x16x32_bf16((a_), (b_), (c_), 0, 0, 0)

__device__ __forceinline__ void load_lds16(const void* g, void* l) {
    __builtin_amdgcn_global_load_lds(
        (const __attribute__((address_space(1))) void*)g,
        (__attribute__((address_space(3))) void*)l,
        16 /*bytes*/, 0 /*offset*/, 0 /*aux*/);
}

// ---- B-only fp32->bf16 convert (A is consumed fp32 by the GEMM).
__global__ void cvt_b(const float* __restrict__ B, uint4* __restrict__ Bo,
                      long n8) {
    const long stride = (long)gridDim.x * blockDim.x;
    for (long i = (long)blockIdx.x * blockDim.x + threadIdx.x; i < n8;
         i += stride) {
        const float4* p = (const float4*)B + i * 2;
        const float4 a = p[0];
        const float4 b = p[1];
        union { __hip_bfloat16 h[8]; uint4 u; } o;
        o.h[0] = __float2bfloat16(a.x); o.h[1] = __float2bfloat16(a.y);
        o.h[2] = __float2bfloat16(a.z); o.h[3] = __float2bfloat16(a.w);
        o.h[4] = __float2bfloat16(b.x); o.h[5] = __float2bfloat16(b.y);
        o.h[6] = __float2bfloat16(b.z); o.h[7] = __float2bfloat16(b.w);
        Bo[i] = o.u;
    }
}

__global__ __launch_bounds__(512, 2) void gemm_bt_pipe(
    const float* __restrict__ Af,   // [M,K] fp32 (converted in-kernel)
    const __bf16* __restrict__ B,   // [N,K] bf16
    float* __restrict__ C,          // [M,N] fp32
    int M, int N, int K) {
    // single smem block: ring buffers in the loop, reduction scratch after.
    __shared__ __align__(16) unsigned char smem[147456];  // 144 KiB
    __bf16* As = (__bf16*)smem;                  // 3 * 256*64*2 = 96 KiB
    __bf16* Bs = (__bf16*)(smem + 98304);        // 3 * 128*64*2 = 48 KiB

    const int tid = threadIdx.x;
    const int wave = tid >> 6;
    const int lane = tid & 63;

    // ---- XCD-bijective swizzle: XCD x owns a 4bm x 8bn chunk.
    const int nbn = N / BN;
    const int nbm = M / BM;
    const int L = (int)blockIdx.x;
    int bm, bn;
    if ((nbm & 7) == 0) {
        const int x = L & 7;
        const int s = L >> 3;
        bm = x * (nbm >> 3) + s / nbn;
        bn = s % nbn;
    } else {
        bm = L / nbn;
        bn = L % nbn;
    }

    // ---- staging geometry: row = 64 bf16 = 8 chunks of 16B.
    const int srow = tid >> 3;                    // row within round (0..63)
    const int chk = tid & 7;                      // linear chunk (global side)
    const int schk = chk ^ (srow & 7);            // swizzled LDS slot
    // A fp32: linear global read (coalesced), swizzle applied at ds_write.
    const float* ga32 = Af + ((size_t)bm * BM + srow) * (size_t)K + chk * 8;
    // B bf16: pre-swizzled global fetch feeds gload_lds's linear placement.
    const __bf16* gb = B + ((size_t)bn * BN + srow) * (size_t)K + schk * 8;
    const size_t g64 = (size_t)64 * K;            // 64-row advance per round
    const int ldst = tid * 8;                     // B LDS elem offset/round
    const int lasw = srow * 64 + schk * 8;        // A LDS elem offset (r adds 4096)

    // ---- fragment addressing: spatial slot s = wave&3 -> 128x64 tile at
    // (s>>1)*128, (s&1)*64; K-half wk = wave>>2 -> chunks 4wk..4wk+3.
    const int ws = wave & 3;
    const int wk = wave >> 2;
    const int wm = (ws >> 1) << 7;    // 0,128
    const int wn = (ws & 1) << 6;     // 0,64
    const int fr = lane & 15;
    const int qd = lane >> 4;
    const int r7 = fr & 7;
    const int sl = ((qd + 4 * wk) ^ r7) << 3;     // swizzled 16B slot

    f32x4 acc[8][4];
#pragma unroll
    for (int i = 0; i < 8; ++i)
#pragma unroll
        for (int j = 0; j < 4; ++j) acc[i][j] = (f32x4){0.f, 0.f, 0.f, 0.f};

    const int NT = K / BK;  // 64

    float4 areg[8];
#define ISSUE_A(kc)                                                           \
    do {                                                                      \
        _Pragma("unroll") for (int r = 0; r < 4; ++r) {                       \
            const float* p_ = ga32 + (size_t)r * 64 * K + (kc);               \
            areg[2 * r] = *(const float4*)p_;                                 \
            areg[2 * r + 1] = *(const float4*)(p_ + 4);                       \
        }                                                                     \
    } while (0)
#define CVT_WRITE_A(dst_)                                                     \
    do {                                                                      \
        _Pragma("unroll") for (int r = 0; r < 4; ++r) {                       \
            union { __hip_bfloat162 h2[4]; uint4 u; } o_;                     \
            o_.h2[0] = __float22bfloat162_rn(                                 \
                make_float2(areg[2 * r].x, areg[2 * r].y));                   \
            o_.h2[1] = __float22bfloat162_rn(                                 \
                make_float2(areg[2 * r].z, areg[2 * r].w));                   \
            o_.h2[2] = __float22bfloat162_rn(                                 \
                make_float2(areg[2 * r + 1].x, areg[2 * r + 1].y));           \
            o_.h2[3] = __float22bfloat162_rn(                                 \
                make_float2(areg[2 * r + 1].z, areg[2 * r + 1].w));           \
            *(uint4*)((dst_) + r * 4096 + lasw) = o_.u;                       \
        }                                                                     \
    } while (0)

    // ---- prologue: A0,A1 cvt->LDS; B0,B1 gload; A2 in flight.
    ISSUE_A(0);
    asm volatile("s_waitcnt vmcnt(0)" ::: "memory");
    CVT_WRITE_A(As);
    ISSUE_A(BK);
    asm volatile("s_waitcnt vmcnt(0)" ::: "memory");
    CVT_WRITE_A(As + BM * BK);
#pragma unroll
    for (int r = 0; r < 2; ++r) load_lds16(gb + r * g64, Bs + ldst + r * 4096);
#pragma unroll
    for (int r = 0; r < 2; ++r)
        load_lds16(gb + r * g64 + BK, Bs + BN * BK + ldst + r * 4096);
    ISSUE_A(2 * BK);
    asm volatile("s_waitcnt vmcnt(8)" ::: "memory");  // B0,B1 landed
    asm volatile("s_waitcnt lgkmcnt(0)" ::: "memory");
    __builtin_amdgcn_s_barrier();
    asm volatile("" ::: "memory");

    int cur = 0, nx = 2;
    for (int t = 0; t < NT; ++t) {
        const __bf16* as = As + cur * (BM * BK);
        const __bf16* bs = Bs + cur * (BN * BK);
        __bf16* asw = As + nx * (BM * BK);
        __bf16* bsw = Bs + nx * (BN * BK);
        const bool pf = (t + 2 < NT);

        // ---- fragment reads: 12 ds_read_b128
        bf16x8 af[8], bf[4];
#pragma unroll
        for (int j = 0; j < 4; ++j)
            bf[j] = *(const bf16x8*)(bs + (wn + j * 16 + fr) * BK + sl);
#pragma unroll
        for (int i = 0; i < 8; ++i)
            af[i] = *(const bf16x8*)(as + (wm + i * 16 + fr) * BK + sl);

        // ---- issue B gload for tile t+2 into ring buffer nx
        if (pf) {
            const size_t kg = (size_t)(t + 2) * BK;
#pragma unroll
            for (int r = 0; r < 2; ++r)
                load_lds16(gb + r * g64 + kg, bsw + ldst + r * 4096);
        }

        // ---- single 32-MFMA cluster (K-half wk)
        __builtin_amdgcn_s_setprio(1);
#pragma unroll
        for (int i = 0; i < 8; ++i)
#pragma unroll
            for (int j = 0; j < 4; ++j)
                acc[i][j] = MFMA16(af[i], bf[j], acc[i][j]);
        __builtin_amdgcn_s_setprio(0);

        // ---- A staging: wait A(t+2) regs (2 younger B-gloads outstanding),
        // cvt+swizzled ds_write into nx, then issue A(t+3) loads.
        if (pf) {
            asm volatile("s_waitcnt vmcnt(2)" ::: "memory");
            CVT_WRITE_A(asw);
            if (t + 3 < NT) ISSUE_A((size_t)(t + 3) * BK);
        } else {
            asm volatile("s_waitcnt vmcnt(0)" ::: "memory");  // tail drain
        }

        // ---- tile boundary: publish ds_writes + bound drift.
        if (t + 1 < NT) {
            asm volatile("s_waitcnt lgkmcnt(0)" ::: "memory");
            __builtin_amdgcn_s_barrier();
            asm volatile("" ::: "memory");
        }
        cur = (cur == NBUF - 1) ? 0 : cur + 1;
        nx = (nx == NBUF - 1) ? 0 : nx + 1;
    }

    // ---- cross-wave K-reduction: wk=1 waves dump acc, wk=0 partners add.
    float* red = (float*)smem;
    __syncthreads();
    if (wk == 1) {
        float* dst = red + ws * 8192;
#pragma unroll
        for (int i = 0; i < 8; ++i)
#pragma unroll
            for (int j = 0; j < 4; ++j)
                *(f32x4*)(dst + (i * 4 + j) * 256 + lane * 4) = acc[i][j];
    }
    __syncthreads();
    if (wk == 0) {
        const float* src = red + ws * 8192;
#pragma unroll
        for (int i = 0; i < 8; ++i)
#pragma unroll
            for (int j = 0; j < 4; ++j) {
                f32x4 v = *(const f32x4*)(src + (i * 4 + j) * 256 + lane * 4);
                acc[i][j] += v;
            }

        // ---- epilogue: C/D layout col=lane&15, row=(lane>>4)*4+reg
        const int cq = qd << 2;
        float* Cbase = C + ((size_t)bm * BM + wm + cq) * (size_t)N +
                       (size_t)bn * BN + wn + fr;
#pragma unroll
        for (int i = 0; i < 8; ++i)
#pragma unroll
            for (int r = 0; r < 4; ++r) {
                float* row = Cbase + (size_t)(16 * i + r) * N;
#pragma unroll
                for (int j = 0; j < 4; ++j) row[16 * j] = acc[i][j][r];
            }
    }
}

// Fallback if ws too small: fused-convert GEMM (BK=32), plain stores.
__global__ __launch_bounds__(256, 2) void gemm_bt_f32in(
    const float* __restrict__ A, const float* __restrict__ B,
    float* __restrict__ C, int M, int N, int K) {
    __shared__ __bf16 As[TM * 32];
    __shared__ __bf16 Bs[TN * 32];

    const int tid = threadIdx.x;
    const int wave = tid >> 6;
    const int lane = tid & 63;
    const int bn = blockIdx.x;
    const int bm = blockIdx.y;

    const int frow = tid >> 3;
    const int fcol = (tid & 7) << 2;
    const float* gaf = A + ((size_t)bm * TM + frow) * (size_t)K + fcol;
    const float* gbf = B + ((size_t)bn * TN + frow) * (size_t)K + fcol;

    const int wm = (wave >> 1) << 6;
    const int wn = (wave & 1) << 6;
    const int fr = lane & 15;
    const int fk = (lane >> 4) << 3;
    const __bf16* pa = As + (wm + fr) * 32 + fk;
    const __bf16* pb = Bs + (wn + fr) * 32 + fk;

    f32x4 acc[4][4];
#pragma unroll
    for (int i = 0; i < 4; ++i)
#pragma unroll
        for (int j = 0; j < 4; ++j) acc[i][j] = (f32x4){0.f, 0.f, 0.f, 0.f};

    for (int k0 = 0; k0 < K; k0 += 32) {
#pragma unroll
        for (int rd = 0; rd < 4; ++rd) {
            float4 va = *(const float4*)(gaf + (size_t)(rd * 32) * K + k0);
            float4 vb = *(const float4*)(gbf + (size_t)(rd * 32) * K + k0);
            union { __hip_bfloat162 h2[2]; uint2 u; } oa, ob;
            oa.h2[0] = __float22bfloat162_rn(make_float2(va.x, va.y));
            oa.h2[1] = __float22bfloat162_rn(make_float2(va.z, va.w));
            ob.h2[0] = __float22bfloat162_rn(make_float2(vb.x, vb.y));
            ob.h2[1] = __float22bfloat162_rn(make_float2(vb.z, vb.w));
            *(uint2*)(As + (frow + rd * 32) * 32 + fcol) = oa.u;
            *(uint2*)(Bs + (frow + rd * 32) * 32 + fcol) = ob.u;
        }
        __syncthreads();

        bf16x8 af[4], bfr[4];
#pragma unroll
        for (int i = 0; i < 4; ++i) af[i] = *(const bf16x8*)(pa + i * (16 * 32));
#pragma unroll
        for (int j = 0; j < 4; ++j) bfr[j] = *(const bf16x8*)(pb + j * (16 * 32));
#pragma unroll
        for (int i = 0; i < 4; ++i)
#pragma unroll
            for (int j = 0; j < 4; ++j)
                acc[i][j] = __builtin_amdgcn_mfma_f32_16x16x32_bf16(
                    af[i], bfr[j], acc[i][j], 0, 0, 0);
        __syncthreads();
    }

    const int cq = (lane >> 4) << 2;
    float* Cbase = C + ((size_t)bm * TM + wm + cq) * (size_t)N +
                   (size_t)bn * TN + wn + fr;
#pragma unroll
    for (int i = 0; i < 4; ++i)
#pragma unroll
        for (int r = 0; r < 4; ++r) {
            float* row = Cbase + (size_t)(16 * i + r) * N;
#pragma unroll
            for (int j = 0; j < 4; ++j) row[16 * j] = acc[i][j][r];
        }
}

extern "C" void kernel_launch(void* const* d_in, const int* in_sizes, int n_in,
                              void* d_out, int out_size, void* d_ws,
                              size_t ws_size, hipStream_t stream) {
    const float* A = (const float*)d_in[0];  // [M,K] (all_gather = reshape)
    const float* B = (const float*)d_in[1];  // [N,K]
    float* C = (float*)d_out;

    const int K = 4096;
    const int aN = in_sizes[0];
    const int bN = in_sizes[1];
    const int M = aN / K;  // 8192
    const int N = bN / K;  // 1024

    const size_t need = (size_t)bN * sizeof(__hip_bfloat16);  // B only

    if (ws_size >= need && (M % BM) == 0 && (N % BN) == 0 && K >= 4 * BK) {
        __hip_bfloat16* Bbf = (__hip_bfloat16*)d_ws;
        cvt_b<<<(unsigned)((bN / 8 + 255) / 256), 256, 0, stream>>>(
            B, (uint4*)Bbf, (long)(bN / 8));
        dim3 grid((unsigned)((M / BM) * (N / BN)));  // 256 = 1 block/CU
        gemm_bt_pipe<<<grid, 512, 0, stream>>>(A, (const __bf16*)Bbf, C, M, N,
                                               K);
    } else {
        dim3 grid(N / TN, M / TM);
        gemm_bt_f32in<<<grid, 256, 0, stream>>>(A, B, C, M, N, K);
    }
}

// Round 6
// 279.740 us; speedup vs baseline: 1.0450x; 1.0450x over previous
//
#include <hip/hip_runtime.h>
#include <hip/hip_bf16.h>

// C[M,N] = A[M,K] @ B[N,K]^T, fp32 in/out, bf16 MFMA.
// R6: R5's fused A-path (fp32 reg-stage -> cvt -> swizzled ds_write, saves
//   the 36us cvt-A pass) with the staging cluster moved from POST-MFMA to
//   PRE-MFMA (T14 issue-early/write-late). R5's 147us regression was the
//   serial tail {vmcnt; cvt; ds_write; lgkm0} between MFMA and barrier in
//   8-wave lockstep; now ds_writes drain UNDER the 32-MFMA cluster and the
//   boundary is a satisfied counted wait. A-reg waits are compiler-placed
//   (it tracks global_load AND global_load_lds in its vmcnt model).
// GEMM: 256x128/BK=64, 512 thr = 8 waves, grid 256 = 1 block/CU,
//   2 waves/SIMD. K-SPLIT WAVE PAIRS: 4 spatial 128x64 tiles x 2 K-halves;
//   12 ds_read_b128 per 32 MFMA; cross-wave add at end. 3-buffer LDS ring
//   (144 KiB), ONE barrier per K-tile (staged buffer (t+2)%3 was last read
//   at t-1, published by the t-1 boundary barrier -> pre-MFMA writes safe).
//   Boundary s_waitcnt vmcnt(10) lgkmcnt(0): leaves A(t+3)x8 + B(t+2)x2 in
//   flight, guarantees B(t+1) in LDS. Tail (t>=NT-3) drains vmcnt(0).
//   XOR bank-swizzle both sides (verified, 0 conflicts). XCD-bijective
//   block swizzle (fetch = compulsory). B via gload_lds + tiny cvt_b (4us).

typedef __bf16 bf16x8 __attribute__((ext_vector_type(8)));
typedef float f32x4 __attribute__((ext_vector_type(4)));

#define BM 256
#define BN 128
#define BK 64
#define NBUF 3
// fallback tile
#define TM 128
#define TN 128

#define MFMA16(a_, b_, c_) \
    __builtin_amdgcn_mfma_f32_16x16x32_bf16((a_), (b_), (c_), 0, 0, 0)

__device__ __forceinline__ void load_lds16(const void* g, void* l) {
    __builtin_amdgcn_global_load_lds(
        (const __attribute__((address_space(1))) void*)g,
        (__attribute__((address_space(3))) void*)l,
        16 /*bytes*/, 0 /*offset*/, 0 /*aux*/);
}

// ---- B-only fp32->bf16 convert (A is consumed fp32 by the GEMM).
__global__ void cvt_b(const float* __restrict__ B, uint4* __restrict__ Bo,
                      long n8) {
    const long stride = (long)gridDim.x * blockDim.x;
    for (long i = (long)blockIdx.x * blockDim.x + threadIdx.x; i < n8;
         i += stride) {
        const float4* p = (const float4*)B + i * 2;
        const float4 a = p[0];
        const float4 b = p[1];
        union { __hip_bfloat16 h[8]; uint4 u; } o;
        o.h[0] = __float2bfloat16(a.x); o.h[1] = __float2bfloat16(a.y);
        o.h[2] = __float2bfloat16(a.z); o.h[3] = __float2bfloat16(a.w);
        o.h[4] = __float2bfloat16(b.x); o.h[5] = __float2bfloat16(b.y);
        o.h[6] = __float2bfloat16(b.z); o.h[7] = __float2bfloat16(b.w);
        Bo[i] = o.u;
    }
}

__global__ __launch_bounds__(512, 2) void gemm_bt_pipe(
    const float* __restrict__ Af,   // [M,K] fp32 (converted in-kernel)
    const __bf16* __restrict__ B,   // [N,K] bf16
    float* __restrict__ C,          // [M,N] fp32
    int M, int N, int K) {
    // single smem block: ring buffers in the loop, reduction scratch after.
    __shared__ __align__(16) unsigned char smem[147456];  // 144 KiB
    __bf16* As = (__bf16*)smem;                  // 3 * 256*64*2 = 96 KiB
    __bf16* Bs = (__bf16*)(smem + 98304);        // 3 * 128*64*2 = 48 KiB

    const int tid = threadIdx.x;
    const int wave = tid >> 6;
    const int lane = tid & 63;

    // ---- XCD-bijective swizzle: XCD x owns a 4bm x 8bn chunk.
    const int nbn = N / BN;
    const int nbm = M / BM;
    const int L = (int)blockIdx.x;
    int bm, bn;
    if ((nbm & 7) == 0) {
        const int x = L & 7;
        const int s = L >> 3;
        bm = x * (nbm >> 3) + s / nbn;
        bn = s % nbn;
    } else {
        bm = L / nbn;
        bn = L % nbn;
    }

    // ---- staging geometry: row = 64 bf16 = 8 chunks of 16B.
    const int srow = tid >> 3;                    // row within round (0..63)
    const int chk = tid & 7;                      // linear chunk (global side)
    const int schk = chk ^ (srow & 7);            // swizzled LDS slot
    // A fp32: linear global read (coalesced), swizzle applied at ds_write.
    const float* ga32 = Af + ((size_t)bm * BM + srow) * (size_t)K + chk * 8;
    // B bf16: pre-swizzled global fetch feeds gload_lds's linear placement.
    const __bf16* gb = B + ((size_t)bn * BN + srow) * (size_t)K + schk * 8;
    const size_t g64 = (size_t)64 * K;            // 64-row advance per round
    const int ldst = tid * 8;                     // B LDS elem offset/round
    const int lasw = srow * 64 + schk * 8;        // A LDS elem offset (+r*4096)

    // ---- fragment addressing: spatial slot s = wave&3 -> 128x64 tile at
    // (s>>1)*128, (s&1)*64; K-half wk = wave>>2 -> chunks 4wk..4wk+3.
    const int ws = wave & 3;
    const int wk = wave >> 2;
    const int wm = (ws >> 1) << 7;    // 0,128
    const int wn = (ws & 1) << 6;     // 0,64
    const int fr = lane & 15;
    const int qd = lane >> 4;
    const int r7 = fr & 7;
    const int sl = ((qd + 4 * wk) ^ r7) << 3;     // swizzled 16B slot

    f32x4 acc[8][4];
#pragma unroll
    for (int i = 0; i < 8; ++i)
#pragma unroll
        for (int j = 0; j < 4; ++j) acc[i][j] = (f32x4){0.f, 0.f, 0.f, 0.f};

    const int NT = K / BK;  // 64

    float4 areg[8];
#define ISSUE_A(kc)                                                           \
    do {                                                                      \
        _Pragma("unroll") for (int r = 0; r < 4; ++r) {                       \
            const float* p_ = ga32 + (size_t)r * 64 * K + (kc);               \
            areg[2 * r] = *(const float4*)p_;                                 \
            areg[2 * r + 1] = *(const float4*)(p_ + 4);                       \
        }                                                                     \
    } while (0)
#define CVT_WRITE_A(dst_)                                                     \
    do {                                                                      \
        _Pragma("unroll") for (int r = 0; r < 4; ++r) {                       \
            union { __hip_bfloat162 h2[4]; uint4 u; } o_;                     \
            o_.h2[0] = __float22bfloat162_rn(                                 \
                make_float2(areg[2 * r].x, areg[2 * r].y));                   \
            o_.h2[1] = __float22bfloat162_rn(                                 \
                make_float2(areg[2 * r].z, areg[2 * r].w));                   \
            o_.h2[2] = __float22bfloat162_rn(                                 \
                make_float2(areg[2 * r + 1].x, areg[2 * r + 1].y));           \
            o_.h2[3] = __float22bfloat162_rn(                                 \
                make_float2(areg[2 * r + 1].z, areg[2 * r + 1].w));           \
            *(uint4*)((dst_) + r * 4096 + lasw) = o_.u;                       \
        }                                                                     \
    } while (0)

    // ---- prologue: A0,A1 cvt->LDS; B0,B1 issued BEFORE A2 so the counted
    // wait vmcnt(10) drains B0 (and older) while A2x8 + B1x2 stay in flight
    // -> entry queue matches steady state [A(t+2)x8, B(t+1)x2].
    ISSUE_A(0);
    CVT_WRITE_A(As);                       // compiler inserts exact A0 wait
    ISSUE_A(BK);
    CVT_WRITE_A(As + BM * BK);             // compiler inserts exact A1 wait
#pragma unroll
    for (int r = 0; r < 2; ++r) load_lds16(gb + r * g64, Bs + ldst + r * 4096);
    ISSUE_A(2 * BK);
#pragma unroll
    for (int r = 0; r < 2; ++r)
        load_lds16(gb + r * g64 + BK, Bs + BN * BK + ldst + r * 4096);
    asm volatile("s_waitcnt vmcnt(10) lgkmcnt(0)" ::: "memory");
    __builtin_amdgcn_s_barrier();
    asm volatile("" ::: "memory");

    int cur = 0, nx = 2;
    for (int t = 0; t < NT; ++t) {
        const __bf16* as = As + cur * (BM * BK);
        const __bf16* bs = Bs + cur * (BN * BK);
        __bf16* asw = As + nx * (BM * BK);
        __bf16* bsw = Bs + nx * (BN * BK);

        // ---- fragment reads: 12 ds_read_b128 (feed MFMA soonest)
        bf16x8 af[8], bf[4];
#pragma unroll
        for (int j = 0; j < 4; ++j)
            bf[j] = *(const bf16x8*)(bs + (wn + j * 16 + fr) * BK + sl);
#pragma unroll
        for (int i = 0; i < 8; ++i)
            af[i] = *(const bf16x8*)(as + (wm + i * 16 + fr) * BK + sl);

        // ---- staging cluster at tile TOP (T14): cvt A(t+2) (regs issued
        // at t-1; compiler places the counted wait), swizzled ds_write into
        // ring buffer nx=(t-1)%3 (safe: last read at t-1, published by the
        // t-1 boundary barrier), then re-issue A(t+3) into the same bank,
        // then B(t+2) gloads. ds_writes drain under the MFMA cluster.
        if (t + 2 < NT) {
            CVT_WRITE_A(asw);
            if (t + 3 < NT) ISSUE_A((size_t)(t + 3) * BK);
            const size_t kg = (size_t)(t + 2) * BK;
#pragma unroll
            for (int r = 0; r < 2; ++r)
                load_lds16(gb + r * g64 + kg, bsw + ldst + r * 4096);
        }

        // ---- single 32-MFMA cluster (K-half wk)
        __builtin_amdgcn_s_setprio(1);
#pragma unroll
        for (int i = 0; i < 8; ++i)
#pragma unroll
            for (int j = 0; j < 4; ++j)
                acc[i][j] = MFMA16(af[i], bf[j], acc[i][j]);
        __builtin_amdgcn_s_setprio(0);

        // ---- tile boundary: counted wait leaves A(t+3)x8 + B(t+2)x2 in
        // flight, guarantees B(t+1) landed; lgkm drains ds_writes (already
        // done under MFMA). Barrier publishes across waves.
        if (t + 1 < NT) {
            if (t + 3 < NT)
                asm volatile("s_waitcnt vmcnt(10) lgkmcnt(0)" ::: "memory");
            else
                asm volatile("s_waitcnt vmcnt(0) lgkmcnt(0)" ::: "memory");
            __builtin_amdgcn_s_barrier();
            asm volatile("" ::: "memory");
        }
        cur = (cur == NBUF - 1) ? 0 : cur + 1;
        nx = (nx == NBUF - 1) ? 0 : nx + 1;
    }

    // ---- cross-wave K-reduction: wk=1 waves dump acc, wk=0 partners add.
    float* red = (float*)smem;
    __syncthreads();
    if (wk == 1) {
        float* dst = red + ws * 8192;
#pragma unroll
        for (int i = 0; i < 8; ++i)
#pragma unroll
            for (int j = 0; j < 4; ++j)
                *(f32x4*)(dst + (i * 4 + j) * 256 + lane * 4) = acc[i][j];
    }
    __syncthreads();
    if (wk == 0) {
        const float* src = red + ws * 8192;
#pragma unroll
        for (int i = 0; i < 8; ++i)
#pragma unroll
            for (int j = 0; j < 4; ++j) {
                f32x4 v = *(const f32x4*)(src + (i * 4 + j) * 256 + lane * 4);
                acc[i][j] += v;
            }

        // ---- epilogue: C/D layout col=lane&15, row=(lane>>4)*4+reg
        const int cq = qd << 2;
        float* Cbase = C + ((size_t)bm * BM + wm + cq) * (size_t)N +
                       (size_t)bn * BN + wn + fr;
#pragma unroll
        for (int i = 0; i < 8; ++i)
#pragma unroll
            for (int r = 0; r < 4; ++r) {
                float* row = Cbase + (size_t)(16 * i + r) * N;
#pragma unroll
                for (int j = 0; j < 4; ++j) row[16 * j] = acc[i][j][r];
            }
    }
}

// Fallback if ws too small: fused-convert GEMM (BK=32), plain stores.
__global__ __launch_bounds__(256, 2) void gemm_bt_f32in(
    const float* __restrict__ A, const float* __restrict__ B,
    float* __restrict__ C, int M, int N, int K) {
    __shared__ __bf16 As[TM * 32];
    __shared__ __bf16 Bs[TN * 32];

    const int tid = threadIdx.x;
    const int wave = tid >> 6;
    const int lane = tid & 63;
    const int bn = blockIdx.x;
    const int bm = blockIdx.y;

    const int frow = tid >> 3;
    const int fcol = (tid & 7) << 2;
    const float* gaf = A + ((size_t)bm * TM + frow) * (size_t)K + fcol;
    const float* gbf = B + ((size_t)bn * TN + frow) * (size_t)K + fcol;

    const int wm = (wave >> 1) << 6;
    const int wn = (wave & 1) << 6;
    const int fr = lane & 15;
    const int fk = (lane >> 4) << 3;
    const __bf16* pa = As + (wm + fr) * 32 + fk;
    const __bf16* pb = Bs + (wn + fr) * 32 + fk;

    f32x4 acc[4][4];
#pragma unroll
    for (int i = 0; i < 4; ++i)
#pragma unroll
        for (int j = 0; j < 4; ++j) acc[i][j] = (f32x4){0.f, 0.f, 0.f, 0.f};

    for (int k0 = 0; k0 < K; k0 += 32) {
#pragma unroll
        for (int rd = 0; rd < 4; ++rd) {
            float4 va = *(const float4*)(gaf + (size_t)(rd * 32) * K + k0);
            float4 vb = *(const float4*)(gbf + (size_t)(rd * 32) * K + k0);
            union { __hip_bfloat162 h2[2]; uint2 u; } oa, ob;
            oa.h2[0] = __float22bfloat162_rn(make_float2(va.x, va.y));
            oa.h2[1] = __float22bfloat162_rn(make_float2(va.z, va.w));
            ob.h2[0] = __float22bfloat162_rn(make_float2(vb.x, vb.y));
            ob.h2[1] = __float22bfloat162_rn(make_float2(vb.z, vb.w));
            *(uint2*)(As + (frow + rd * 32) * 32 + fcol) = oa.u;
            *(uint2*)(Bs + (frow + rd * 32) * 32 + fcol) = ob.u;
        }
        __syncthreads();

        bf16x8 af[4], bfr[4];
#pragma unroll
        for (int i = 0; i < 4; ++i) af[i] = *(const bf16x8*)(pa + i * (16 * 32));
#pragma unroll
        for (int j = 0; j < 4; ++j) bfr[j] = *(const bf16x8*)(pb + j * (16 * 32));
#pragma unroll
        for (int i = 0; i < 4; ++i)
#pragma unroll
            for (int j = 0; j < 4; ++j)
                acc[i][j] = __builtin_amdgcn_mfma_f32_16x16x32_bf16(
                    af[i], bfr[j], acc[i][j], 0, 0, 0);
        __syncthreads();
    }

    const int cq = (lane >> 4) << 2;
    float* Cbase = C + ((size_t)bm * TM + wm + cq) * (size_t)N +
                   (size_t)bn * TN + wn + fr;
#pragma unroll
    for (int i = 0; i < 4; ++i)
#pragma unroll
        for (int r = 0; r < 4; ++r) {
            float* row = Cbase + (size_t)(16 * i + r) * N;
#pragma unroll
            for (int j = 0; j < 4; ++j) row[16 * j] = acc[i][j][r];
        }
}

extern "C" void kernel_launch(void* const* d_in, const int* in_sizes, int n_in,
                              void* d_out, int out_size, void* d_ws,
                              size_t ws_size, hipStream_t stream) {
    const float* A = (const float*)d_in[0];  // [M,K] (all_gather = reshape)
    const float* B = (const float*)d_in[1];  // [N,K]
    float* C = (float*)d_out;

    const int K = 4096;
    const int aN = in_sizes[0];
    const int bN = in_sizes[1];
    const int M = aN / K;  // 8192
    const int N = bN / K;  // 1024

    const size_t need = (size_t)bN * sizeof(__hip_bfloat16);  // B only

    if (ws_size >= need && (M % BM) == 0 && (N % BN) == 0 && K >= 4 * BK) {
        __hip_bfloat16* Bbf = (__hip_bfloat16*)d_ws;
        cvt_b<<<(unsigned)((bN / 8 + 255) / 256), 256, 0, stream>>>(
            B, (uint4*)Bbf, (long)(bN / 8));
        dim3 grid((unsigned)((M / BM) * (N / BN)));  // 256 = 1 block/CU
        gemm_bt_pipe<<<grid, 512, 0, stream>>>(A, (const __bf16*)Bbf, C, M, N,
                                               K);
    } else {
        dim3 grid(N / TN, M / TM);
        gemm_bt_f32in<<<grid, 256, 0, stream>>>(A, B, C, M, N, K);
    }
}

// Round 7
// 276.719 us; speedup vs baseline: 1.0564x; 1.0109x over previous
//
#include <hip/hip_runtime.h>
#include <hip/hip_bf16.h>

// C[M,N] = A[M,K] @ B[N,K]^T, fp32 in/out, bf16 MFMA.
// R7 = revert to verified R4 artifact (best: 276.7us e2e, GEMM <78us) after
//   two failed cvt-fusion attempts (R5: 147us, R6: 128us — the fused A-path's
//   areg-wait + cvt VALU + ds_write sits on the lockstep critical path and
//   cannot be hidden at 2 waves/SIMD). Single change vs R4: the boundary
//   s_waitcnt vmcnt(6) moves from AFTER the MFMA cluster to BEFORE it —
//   count-invariant (this tile's 6 staging issues are already in the queue:
//   12 outstanding -> vmcnt(6) == "tile t+1 landed"), so the drain overlaps
//   MFMA issue instead of sitting naked before the barrier.
// Phase 1: fused fp32->bf16 convert of A,B into d_ws (~36us, HBM-bound).
// Phase 2: 256x128/BK=64 GEMM, 512 thr = 8 waves, grid 256 = 1 block/CU,
//   2 waves/SIMD (R3: 1 wave/SIMD is fatal). K-SPLIT WAVE PAIRS: 4 spatial
//   128x64 tiles x 2 K-halves; 12 ds_read_b128 per 32 MFMA (0.375 ratio);
//   cross-wave add once at end. 3-buffer LDS ring (144 KiB), depth-2
//   global_load_lds prefetch, ONE barrier per K-tile (ring slack bounds
//   drift; staged buffer was last read at t-1). Counted vmcnt only (never 0
//   until tail). XOR bank-swizzle on 16B chunks (slot(c,row)=c^(row&7);
//   staging lane fetches pre-swizzled global chunk; measured 0 conflicts).
//   XCD-bijective block swizzle (FETCH_SIZE 266->65.6 MB = compulsory).

typedef __bf16 bf16x8 __attribute__((ext_vector_type(8)));
typedef float f32x4 __attribute__((ext_vector_type(4)));

#define BM 256
#define BN 128
#define BK 64
#define NBUF 3
// fallback tile
#define TM 128
#define TN 128

#define MFMA16(a_, b_, c_) \
    __builtin_amdgcn_mfma_f32_16x16x32_bf16((a_), (b_), (c_), 0, 0, 0)

__device__ __forceinline__ void load_lds16(const void* g, void* l) {
    __builtin_amdgcn_global_load_lds(
        (const __attribute__((address_space(1))) void*)g,
        (__attribute__((address_space(3))) void*)l,
        16 /*bytes*/, 0 /*offset*/, 0 /*aux*/);
}

// ---- fused convert: A then B, grid-stride.
__global__ void cvt_all(const float* __restrict__ A, uint4* __restrict__ Ao,
                        long nA8, const float* __restrict__ B,
                        uint4* __restrict__ Bo, long nB8) {
    const long stride = (long)gridDim.x * blockDim.x;
    const long tot = nA8 + nB8;
    for (long i = (long)blockIdx.x * blockDim.x + threadIdx.x; i < tot;
         i += stride) {
        const float4* p;
        uint4* d;
        if (i < nA8) {
            p = (const float4*)A + i * 2;
            d = Ao + i;
        } else {
            const long j = i - nA8;
            p = (const float4*)B + j * 2;
            d = Bo + j;
        }
        const float4 a = p[0];
        const float4 b = p[1];
        union { __hip_bfloat16 h[8]; uint4 u; } o;
        o.h[0] = __float2bfloat16(a.x); o.h[1] = __float2bfloat16(a.y);
        o.h[2] = __float2bfloat16(a.z); o.h[3] = __float2bfloat16(a.w);
        o.h[4] = __float2bfloat16(b.x); o.h[5] = __float2bfloat16(b.y);
        o.h[6] = __float2bfloat16(b.z); o.h[7] = __float2bfloat16(b.w);
        *d = o.u;
    }
}

__global__ __launch_bounds__(512, 2) void gemm_bt_pipe(
    const __bf16* __restrict__ A,  // [M,K] bf16
    const __bf16* __restrict__ B,  // [N,K] bf16
    float* __restrict__ C,         // [M,N] fp32
    int M, int N, int K) {
    // single smem block: ring buffers in the loop, reduction scratch after.
    __shared__ __align__(16) unsigned char smem[147456];  // 144 KiB
    __bf16* As = (__bf16*)smem;                  // 3 * 256*64*2 = 96 KiB
    __bf16* Bs = (__bf16*)(smem + 98304);        // 3 * 128*64*2 = 48 KiB

    const int tid = threadIdx.x;
    const int wave = tid >> 6;
    const int lane = tid & 63;

    // ---- XCD-bijective swizzle: XCD x owns a 4bm x 8bn chunk (~16 MB).
    const int nbn = N / BN;
    const int nbm = M / BM;
    const int L = (int)blockIdx.x;
    int bm, bn;
    if ((nbm & 7) == 0) {
        const int x = L & 7;
        const int s = L >> 3;
        bm = x * (nbm >> 3) + s / nbn;
        bn = s % nbn;
    } else {
        bm = L / nbn;
        bn = L % nbn;
    }

    // ---- staging: row = 128 B = 8 chunks; 512 threads cover 64 rows/round.
    // A tile = 4 rounds, B tile = 2 rounds; 6 loads/thread/K-tile.
    const int srow = tid >> 3;                    // row within round (0..63)
    const int schk = (tid & 7) ^ (srow & 7);      // pre-swizzled global chunk
    const __bf16* ga = A + ((size_t)bm * BM + srow) * (size_t)K + schk * 8;
    const __bf16* gb = B + ((size_t)bn * BN + srow) * (size_t)K + schk * 8;
    const size_t g64 = (size_t)64 * K;            // 64-row advance per round
    const int ldst = tid * 8;                     // LDS elem offset in round

    // ---- fragment addressing: spatial slot s = wave&3 -> 128x64 tile at
    // (s>>1)*128, (s&1)*64; K-half wk = wave>>2 -> chunks 4wk..4wk+3.
    const int ws = wave & 3;
    const int wk = wave >> 2;
    const int wm = (ws >> 1) << 7;    // 0,128
    const int wn = (ws & 1) << 6;     // 0,64
    const int fr = lane & 15;
    const int qd = lane >> 4;
    const int r7 = fr & 7;
    const int sl = (((qd + 4 * wk)) ^ r7) << 3;   // swizzled 16B slot

    f32x4 acc[8][4];
#pragma unroll
    for (int i = 0; i < 8; ++i)
#pragma unroll
        for (int j = 0; j < 4; ++j) acc[i][j] = (f32x4){0.f, 0.f, 0.f, 0.f};

    const int NT = K / BK;  // 64

    // ---- prologue: stage tiles 0 and 1 (6 loads each, tile-ordered)
#pragma unroll
    for (int r = 0; r < 4; ++r) load_lds16(ga + r * g64, As + ldst + r * 4096);
#pragma unroll
    for (int r = 0; r < 2; ++r) load_lds16(gb + r * g64, Bs + ldst + r * 4096);
    asm volatile("" ::: "memory");
#pragma unroll
    for (int r = 0; r < 4; ++r)
        load_lds16(ga + r * g64 + BK, As + BM * BK + ldst + r * 4096);
#pragma unroll
    for (int r = 0; r < 2; ++r)
        load_lds16(gb + r * g64 + BK, Bs + BN * BK + ldst + r * 4096);
    asm volatile("s_waitcnt vmcnt(6)" ::: "memory");  // tile 0 resident
    __builtin_amdgcn_s_barrier();
    asm volatile("" ::: "memory");

    int cur = 0, nx = 2;
    for (int t = 0; t < NT; ++t) {
        const __bf16* as = As + cur * (BM * BK);
        const __bf16* bs = Bs + cur * (BN * BK);
        __bf16* asw = As + nx * (BM * BK);
        __bf16* bsw = Bs + nx * (BN * BK);
        const bool pf = (t + 2 < NT);

        // ---- fragment reads: 12 ds_read_b128 (critical path first)
        bf16x8 af[8], bf[4];
#pragma unroll
        for (int j = 0; j < 4; ++j)
            bf[j] = *(const bf16x8*)(bs + (wn + j * 16 + fr) * BK + sl);
#pragma unroll
        for (int i = 0; i < 8; ++i)
            af[i] = *(const bf16x8*)(as + (wm + i * 16 + fr) * BK + sl);

        // ---- stage tile t+2 into buffer (t-1)%3 (read finished at t-1,
        // published by the t-1 boundary barrier).
        if (pf) {
            const size_t kg = (size_t)(t + 2) * BK;
#pragma unroll
            for (int r = 0; r < 4; ++r)
                load_lds16(ga + r * g64 + kg, asw + ldst + r * 4096);
#pragma unroll
            for (int r = 0; r < 2; ++r)
                load_lds16(gb + r * g64 + kg, bsw + ldst + r * 4096);
        }

        // ---- counted drain BEFORE the MFMA cluster (count-invariant:
        // outstanding = t+1's 6 + t+2's 6 -> vmcnt(6) == t+1 landed);
        // the stall overlaps MFMA issue instead of preceding the barrier.
        if (t + 1 < NT) {
            if (pf) asm volatile("s_waitcnt vmcnt(6)" ::: "memory");
            else    asm volatile("s_waitcnt vmcnt(0)" ::: "memory");
        }

        // ---- single 32-MFMA cluster (all independent; K-half wk)
        __builtin_amdgcn_s_setprio(1);
#pragma unroll
        for (int i = 0; i < 8; ++i)
#pragma unroll
            for (int j = 0; j < 4; ++j)
                acc[i][j] = MFMA16(af[i], bf[j], acc[i][j]);
        __builtin_amdgcn_s_setprio(0);

        // ---- tile boundary: bare barrier publishes all waves' t+1 loads
        // and bounds wave drift to < 1 tile (= ring slack).
        if (t + 1 < NT) {
            __builtin_amdgcn_s_barrier();
            asm volatile("" ::: "memory");
        }
        cur = (cur == NBUF - 1) ? 0 : cur + 1;
        nx = (nx == NBUF - 1) ? 0 : nx + 1;
    }

    // ---- cross-wave K-reduction: wk=1 waves dump acc, wk=0 partners add.
    // Reuses ring LDS (4 x 32 KiB = 128 KiB <= 144 KiB).
    float* red = (float*)smem;
    __syncthreads();
    if (wk == 1) {
        float* dst = red + ws * 8192;  // 32 KiB region per spatial slot
#pragma unroll
        for (int i = 0; i < 8; ++i)
#pragma unroll
            for (int j = 0; j < 4; ++j)
                *(f32x4*)(dst + (i * 4 + j) * 256 + lane * 4) = acc[i][j];
    }
    __syncthreads();
    if (wk == 0) {
        const float* src = red + ws * 8192;
#pragma unroll
        for (int i = 0; i < 8; ++i)
#pragma unroll
            for (int j = 0; j < 4; ++j) {
                f32x4 v = *(const f32x4*)(src + (i * 4 + j) * 256 + lane * 4);
                acc[i][j] += v;
            }

        // ---- epilogue: C/D layout col=lane&15, row=(lane>>4)*4+reg
        const int cq = qd << 2;
        float* Cbase = C + ((size_t)bm * BM + wm + cq) * (size_t)N +
                       (size_t)bn * BN + wn + fr;
#pragma unroll
        for (int i = 0; i < 8; ++i)
#pragma unroll
            for (int r = 0; r < 4; ++r) {
                float* row = Cbase + (size_t)(16 * i + r) * N;
#pragma unroll
                for (int j = 0; j < 4; ++j) row[16 * j] = acc[i][j][r];
            }
    }
}

// Fallback if ws too small: fused-convert GEMM (BK=32), plain stores.
__global__ __launch_bounds__(256, 2) void gemm_bt_f32in(
    const float* __restrict__ A, const float* __restrict__ B,
    float* __restrict__ C, int M, int N, int K) {
    __shared__ __bf16 As[TM * 32];
    __shared__ __bf16 Bs[TN * 32];

    const int tid = threadIdx.x;
    const int wave = tid >> 6;
    const int lane = tid & 63;
    const int bn = blockIdx.x;
    const int bm = blockIdx.y;

    const int frow = tid >> 3;
    const int fcol = (tid & 7) << 2;
    const float* gaf = A + ((size_t)bm * TM + frow) * (size_t)K + fcol;
    const float* gbf = B + ((size_t)bn * TN + frow) * (size_t)K + fcol;

    const int wm = (wave >> 1) << 6;
    const int wn = (wave & 1) << 6;
    const int fr = lane & 15;
    const int fk = (lane >> 4) << 3;
    const __bf16* pa = As + (wm + fr) * 32 + fk;
    const __bf16* pb = Bs + (wn + fr) * 32 + fk;

    f32x4 acc[4][4];
#pragma unroll
    for (int i = 0; i < 4; ++i)
#pragma unroll
        for (int j = 0; j < 4; ++j) acc[i][j] = (f32x4){0.f, 0.f, 0.f, 0.f};

    for (int k0 = 0; k0 < K; k0 += 32) {
#pragma unroll
        for (int rd = 0; rd < 4; ++rd) {
            float4 va = *(const float4*)(gaf + (size_t)(rd * 32) * K + k0);
            float4 vb = *(const float4*)(gbf + (size_t)(rd * 32) * K + k0);
            union { __hip_bfloat162 h2[2]; uint2 u; } oa, ob;
            oa.h2[0] = __float22bfloat162_rn(make_float2(va.x, va.y));
            oa.h2[1] = __float22bfloat162_rn(make_float2(va.z, va.w));
            ob.h2[0] = __float22bfloat162_rn(make_float2(vb.x, vb.y));
            ob.h2[1] = __float22bfloat162_rn(make_float2(vb.z, vb.w));
            *(uint2*)(As + (frow + rd * 32) * 32 + fcol) = oa.u;
            *(uint2*)(Bs + (frow + rd * 32) * 32 + fcol) = ob.u;
        }
        __syncthreads();

        bf16x8 af[4], bfr[4];
#pragma unroll
        for (int i = 0; i < 4; ++i) af[i] = *(const bf16x8*)(pa + i * (16 * 32));
#pragma unroll
        for (int j = 0; j < 4; ++j) bfr[j] = *(const bf16x8*)(pb + j * (16 * 32));
#pragma unroll
        for (int i = 0; i < 4; ++i)
#pragma unroll
            for (int j = 0; j < 4; ++j)
                acc[i][j] = __builtin_amdgcn_mfma_f32_16x16x32_bf16(
                    af[i], bfr[j], acc[i][j], 0, 0, 0);
        __syncthreads();
    }

    const int cq = (lane >> 4) << 2;
    float* Cbase = C + ((size_t)bm * TM + wm + cq) * (size_t)N +
                   (size_t)bn * TN + wn + fr;
#pragma unroll
    for (int i = 0; i < 4; ++i)
#pragma unroll
        for (int r = 0; r < 4; ++r) {
            float* row = Cbase + (size_t)(16 * i + r) * N;
#pragma unroll
            for (int j = 0; j < 4; ++j) row[16 * j] = acc[i][j][r];
        }
}

extern "C" void kernel_launch(void* const* d_in, const int* in_sizes, int n_in,
                              void* d_out, int out_size, void* d_ws,
                              size_t ws_size, hipStream_t stream) {
    const float* A = (const float*)d_in[0];  // [M,K] (all_gather = reshape)
    const float* B = (const float*)d_in[1];  // [N,K]
    float* C = (float*)d_out;

    const int K = 4096;
    const int aN = in_sizes[0];
    const int bN = in_sizes[1];
    const int M = aN / K;  // 8192
    const int N = bN / K;  // 1024

    const size_t need = ((size_t)aN + (size_t)bN) * sizeof(__hip_bfloat16);

    if (ws_size >= need && (M % BM) == 0 && (N % BN) == 0) {
        __hip_bfloat16* Abf = (__hip_bfloat16*)d_ws;
        __hip_bfloat16* Bbf = Abf + (size_t)aN;
        cvt_all<<<2048, 256, 0, stream>>>(A, (uint4*)Abf, (long)(aN / 8), B,
                                          (uint4*)Bbf, (long)(bN / 8));
        dim3 grid((unsigned)((M / BM) * (N / BN)));  // 256 = 1 block/CU
        gemm_bt_pipe<<<grid, 512, 0, stream>>>((const __bf16*)Abf,
                                               (const __bf16*)Bbf, C, M, N, K);
    } else {
        dim3 grid(N / TN, M / TM);
        gemm_bt_f32in<<<grid, 256, 0, stream>>>(A, B, C, M, N, K);
    }
}

// Round 8
// 274.789 us; speedup vs baseline: 1.0638x; 1.0070x over previous
//
#include <hip/hip_runtime.h>
#include <hip/hip_bf16.h>

// C[M,N] = A[M,K] @ B[N,K]^T, fp32 in/out, bf16 MFMA.
// R8: test the one mechanism absent since R0 — TWO independent blocks/CU.
//   All R1-R7 designs were 1 block/CU: every vmcnt/barrier stall was
//   block-wide dead time (MfmaUtil pinned 21-35%). R0 (2 blocks/CU) got
//   free cross-block overlap despite worse internals. This round combines
//   K-split read economics (R4's win, 0.375 ds_read/MFMA) with 2 blocks/CU:
//   BM=128xBN=128/BK=64, 256 thr = 4 waves = 2 n-slots x 2 K-halves,
//   NBUF=2 ring (64 KiB <= 80 KiB/block at 2 blocks/CU), grid 512 = 2/CU.
//   Depth-1 prefetch: stage t+1 at top of t, boundary vmcnt(0)+barrier —
//   the exposed drain (~200-500 cyc) is covered by the partner block's
//   MFMAs (independent barrier domains). Ring safety: staged buffer was
//   last read at t-1, published by the t-1 boundary barrier (per-wave
//   ds_reads are register-complete before the barrier). Cross-wave
//   K-reduction at end (2 slots x 32 KiB = ring reuse). XOR bank-swizzle
//   (verified 0 conflicts). XCD-bijective block swizzle. cvt_all unchanged
//   (~36us, HBM-ceiling). Abort: e2e>283 or gemm>80 -> revert to R7.

typedef __bf16 bf16x8 __attribute__((ext_vector_type(8)));
typedef float f32x4 __attribute__((ext_vector_type(4)));

#define BM 128
#define BN 128
#define BK 64
// fallback tile
#define TM 128
#define TN 128

#define MFMA16(a_, b_, c_) \
    __builtin_amdgcn_mfma_f32_16x16x32_bf16((a_), (b_), (c_), 0, 0, 0)

__device__ __forceinline__ void load_lds16(const void* g, void* l) {
    __builtin_amdgcn_global_load_lds(
        (const __attribute__((address_space(1))) void*)g,
        (__attribute__((address_space(3))) void*)l,
        16 /*bytes*/, 0 /*offset*/, 0 /*aux*/);
}

// ---- fused convert: A then B, grid-stride.
__global__ void cvt_all(const float* __restrict__ A, uint4* __restrict__ Ao,
                        long nA8, const float* __restrict__ B,
                        uint4* __restrict__ Bo, long nB8) {
    const long stride = (long)gridDim.x * blockDim.x;
    const long tot = nA8 + nB8;
    for (long i = (long)blockIdx.x * blockDim.x + threadIdx.x; i < tot;
         i += stride) {
        const float4* p;
        uint4* d;
        if (i < nA8) {
            p = (const float4*)A + i * 2;
            d = Ao + i;
        } else {
            const long j = i - nA8;
            p = (const float4*)B + j * 2;
            d = Bo + j;
        }
        const float4 a = p[0];
        const float4 b = p[1];
        union { __hip_bfloat16 h[8]; uint4 u; } o;
        o.h[0] = __float2bfloat16(a.x); o.h[1] = __float2bfloat16(a.y);
        o.h[2] = __float2bfloat16(a.z); o.h[3] = __float2bfloat16(a.w);
        o.h[4] = __float2bfloat16(b.x); o.h[5] = __float2bfloat16(b.y);
        o.h[6] = __float2bfloat16(b.z); o.h[7] = __float2bfloat16(b.w);
        *d = o.u;
    }
}

__global__ __launch_bounds__(256, 2) void gemm_bt_pipe(
    const __bf16* __restrict__ A,  // [M,K] bf16
    const __bf16* __restrict__ B,  // [N,K] bf16
    float* __restrict__ C,         // [M,N] fp32
    int M, int N, int K) {
    // 64 KiB: 2-buffer ring in the loop, reduction scratch after.
    __shared__ __align__(16) unsigned char smem[65536];
    __bf16* As = (__bf16*)smem;                  // 2 * 128*64*2 = 32 KiB
    __bf16* Bs = (__bf16*)(smem + 32768);        // 2 * 128*64*2 = 32 KiB

    const int tid = threadIdx.x;
    const int wave = tid >> 6;
    const int lane = tid & 63;

    // ---- XCD-bijective swizzle: XCD x owns an 8bm x 8bn chunk.
    const int nbn = N / BN;               // 8
    const int nbm = M / BM;               // 64
    const int L = (int)blockIdx.x;
    int bm, bn;
    if ((nbm & 7) == 0) {
        const int x = L & 7;
        const int s = L >> 3;
        bm = x * (nbm >> 3) + s / nbn;
        bn = s % nbn;
    } else {
        bm = L / nbn;
        bn = L % nbn;
    }

    // ---- staging: row = 128 B = 8 chunks; 256 threads cover 32 rows/round.
    // A tile = 4 rounds, B tile = 4 rounds; 8 loads/thread/K-tile.
    const int srow = tid >> 3;                    // row within round (0..31)
    const int schk = (tid & 7) ^ (srow & 7);      // pre-swizzled global chunk
    const __bf16* ga = A + ((size_t)bm * BM + srow) * (size_t)K + schk * 8;
    const __bf16* gb = B + ((size_t)bn * BN + srow) * (size_t)K + schk * 8;
    const size_t g32 = (size_t)32 * K;            // 32-row advance per round
    const int ldst = tid * 8;                     // LDS elem offset in round

    // ---- fragment addressing: n-slot ws = wave&1 -> 128x64 tile at
    // (0, ws*64); K-half wk = wave>>1 -> chunks 4wk..4wk+3.
    const int ws = wave & 1;
    const int wk = wave >> 1;
    const int wn = ws << 6;           // 0,64
    const int fr = lane & 15;
    const int qd = lane >> 4;
    const int r7 = fr & 7;
    const int sl = ((qd + 4 * wk) ^ r7) << 3;     // swizzled 16B slot

    f32x4 acc[8][4];
#pragma unroll
    for (int i = 0; i < 8; ++i)
#pragma unroll
        for (int j = 0; j < 4; ++j) acc[i][j] = (f32x4){0.f, 0.f, 0.f, 0.f};

    const int NT = K / BK;  // 64

    // ---- prologue: stage tile 0 (8 loads), drain, barrier.
#pragma unroll
    for (int r = 0; r < 4; ++r) load_lds16(ga + r * g32, As + ldst + r * 2048);
#pragma unroll
    for (int r = 0; r < 4; ++r) load_lds16(gb + r * g32, Bs + ldst + r * 2048);
    asm volatile("s_waitcnt vmcnt(0)" ::: "memory");
    __builtin_amdgcn_s_barrier();
    asm volatile("" ::: "memory");

    int cur = 0;
    for (int t = 0; t < NT; ++t) {
        const __bf16* as = As + cur * (BM * BK);
        const __bf16* bs = Bs + cur * (BN * BK);
        __bf16* asw = As + (cur ^ 1) * (BM * BK);
        __bf16* bsw = Bs + (cur ^ 1) * (BN * BK);

        // ---- fragment reads: 12 ds_read_b128
        bf16x8 af[8], bf[4];
#pragma unroll
        for (int j = 0; j < 4; ++j)
            bf[j] = *(const bf16x8*)(bs + (wn + j * 16 + fr) * BK + sl);
#pragma unroll
        for (int i = 0; i < 8; ++i)
            af[i] = *(const bf16x8*)(as + (i * 16 + fr) * BK + sl);

        // ---- stage tile t+1 into the other buffer (last read at t-1,
        // published by the t-1 boundary barrier).
        if (t + 1 < NT) {
            const size_t kg = (size_t)(t + 1) * BK;
#pragma unroll
            for (int r = 0; r < 4; ++r)
                load_lds16(ga + r * g32 + kg, asw + ldst + r * 2048);
#pragma unroll
            for (int r = 0; r < 4; ++r)
                load_lds16(gb + r * g32 + kg, bsw + ldst + r * 2048);
        }

        // ---- single 32-MFMA cluster (K-half wk); staging loads fly under.
        __builtin_amdgcn_s_setprio(1);
#pragma unroll
        for (int i = 0; i < 8; ++i)
#pragma unroll
            for (int j = 0; j < 4; ++j)
                acc[i][j] = MFMA16(af[i], bf[j], acc[i][j]);
        __builtin_amdgcn_s_setprio(0);

        // ---- boundary: drain t+1's loads, barrier. The exposed remainder
        // of HBM latency is covered by the partner block on this CU.
        if (t + 1 < NT) {
            asm volatile("s_waitcnt vmcnt(0)" ::: "memory");
            __builtin_amdgcn_s_barrier();
            asm volatile("" ::: "memory");
        }
        cur ^= 1;
    }

    // ---- cross-wave K-reduction: wk=1 waves dump acc, wk=0 partners add.
    // Scratch: 2 slots x 32 KiB = 64 KiB (exact ring reuse).
    float* red = (float*)smem;
    __syncthreads();
    if (wk == 1) {
        float* dst = red + ws * 8192;
#pragma unroll
        for (int i = 0; i < 8; ++i)
#pragma unroll
            for (int j = 0; j < 4; ++j)
                *(f32x4*)(dst + (i * 4 + j) * 256 + lane * 4) = acc[i][j];
    }
    __syncthreads();
    if (wk == 0) {
        const float* src = red + ws * 8192;
#pragma unroll
        for (int i = 0; i < 8; ++i)
#pragma unroll
            for (int j = 0; j < 4; ++j) {
                f32x4 v = *(const f32x4*)(src + (i * 4 + j) * 256 + lane * 4);
                acc[i][j] += v;
            }

        // ---- epilogue: C/D layout col=lane&15, row=(lane>>4)*4+reg
        const int cq = qd << 2;
        float* Cbase = C + ((size_t)bm * BM + cq) * (size_t)N +
                       (size_t)bn * BN + wn + fr;
#pragma unroll
        for (int i = 0; i < 8; ++i)
#pragma unroll
            for (int r = 0; r < 4; ++r) {
                float* row = Cbase + (size_t)(16 * i + r) * N;
#pragma unroll
                for (int j = 0; j < 4; ++j) row[16 * j] = acc[i][j][r];
            }
    }
}

// Fallback if ws too small: fused-convert GEMM (BK=32), plain stores.
__global__ __launch_bounds__(256, 2) void gemm_bt_f32in(
    const float* __restrict__ A, const float* __restrict__ B,
    float* __restrict__ C, int M, int N, int K) {
    __shared__ __bf16 As[TM * 32];
    __shared__ __bf16 Bs[TN * 32];

    const int tid = threadIdx.x;
    const int wave = tid >> 6;
    const int lane = tid & 63;
    const int bn = blockIdx.x;
    const int bm = blockIdx.y;

    const int frow = tid >> 3;
    const int fcol = (tid & 7) << 2;
    const float* gaf = A + ((size_t)bm * TM + frow) * (size_t)K + fcol;
    const float* gbf = B + ((size_t)bn * TN + frow) * (size_t)K + fcol;

    const int wm = (wave >> 1) << 6;
    const int wn = (wave & 1) << 6;
    const int fr = lane & 15;
    const int fk = (lane >> 4) << 3;
    const __bf16* pa = As + (wm + fr) * 32 + fk;
    const __bf16* pb = Bs + (wn + fr) * 32 + fk;

    f32x4 acc[4][4];
#pragma unroll
    for (int i = 0; i < 4; ++i)
#pragma unroll
        for (int j = 0; j < 4; ++j) acc[i][j] = (f32x4){0.f, 0.f, 0.f, 0.f};

    for (int k0 = 0; k0 < K; k0 += 32) {
#pragma unroll
        for (int rd = 0; rd < 4; ++rd) {
            float4 va = *(const float4*)(gaf + (size_t)(rd * 32) * K + k0);
            float4 vb = *(const float4*)(gbf + (size_t)(rd * 32) * K + k0);
            union { __hip_bfloat162 h2[2]; uint2 u; } oa, ob;
            oa.h2[0] = __float22bfloat162_rn(make_float2(va.x, va.y));
            oa.h2[1] = __float22bfloat162_rn(make_float2(va.z, va.w));
            ob.h2[0] = __float22bfloat162_rn(make_float2(vb.x, vb.y));
            ob.h2[1] = __float22bfloat162_rn(make_float2(vb.z, vb.w));
            *(uint2*)(As + (frow + rd * 32) * 32 + fcol) = oa.u;
            *(uint2*)(Bs + (frow + rd * 32) * 32 + fcol) = ob.u;
        }
        __syncthreads();

        bf16x8 af[4], bfr[4];
#pragma unroll
        for (int i = 0; i < 4; ++i) af[i] = *(const bf16x8*)(pa + i * (16 * 32));
#pragma unroll
        for (int j = 0; j < 4; ++j) bfr[j] = *(const bf16x8*)(pb + j * (16 * 32));
#pragma unroll
        for (int i = 0; i < 4; ++i)
#pragma unroll
            for (int j = 0; j < 4; ++j)
                acc[i][j] = __builtin_amdgcn_mfma_f32_16x16x32_bf16(
                    af[i], bfr[j], acc[i][j], 0, 0, 0);
        __syncthreads();
    }

    const int cq = (lane >> 4) << 2;
    float* Cbase = C + ((size_t)bm * TM + wm + cq) * (size_t)N +
                   (size_t)bn * TN + wn + fr;
#pragma unroll
    for (int i = 0; i < 4; ++i)
#pragma unroll
        for (int r = 0; r < 4; ++r) {
            float* row = Cbase + (size_t)(16 * i + r) * N;
#pragma unroll
            for (int j = 0; j < 4; ++j) row[16 * j] = acc[i][j][r];
        }
}

extern "C" void kernel_launch(void* const* d_in, const int* in_sizes, int n_in,
                              void* d_out, int out_size, void* d_ws,
                              size_t ws_size, hipStream_t stream) {
    const float* A = (const float*)d_in[0];  // [M,K] (all_gather = reshape)
    const float* B = (const float*)d_in[1];  // [N,K]
    float* C = (float*)d_out;

    const int K = 4096;
    const int aN = in_sizes[0];
    const int bN = in_sizes[1];
    const int M = aN / K;  // 8192
    const int N = bN / K;  // 1024

    const size_t need = ((size_t)aN + (size_t)bN) * sizeof(__hip_bfloat16);

    if (ws_size >= need && (M % BM) == 0 && (N % BN) == 0) {
        __hip_bfloat16* Abf = (__hip_bfloat16*)d_ws;
        __hip_bfloat16* Bbf = Abf + (size_t)aN;
        cvt_all<<<2048, 256, 0, stream>>>(A, (uint4*)Abf, (long)(aN / 8), B,
                                          (uint4*)Bbf, (long)(bN / 8));
        dim3 grid((unsigned)((M / BM) * (N / BN)));  // 512 = 2 blocks/CU
        gemm_bt_pipe<<<grid, 256, 0, stream>>>((const __bf16*)Abf,
                                               (const __bf16*)Bbf, C, M, N, K);
    } else {
        dim3 grid(N / TN, M / TM);
        gemm_bt_f32in<<<grid, 256, 0, stream>>>(A, B, C, M, N, K);
    }
}